// Round 2
// baseline (313.888 us; speedup 1.0000x reference)
//
#include <hip/hip_runtime.h>
#include <cstdint>
#include <cstddef>

// LSTM cell: B=16384, IN=HID=512.
// Fused bf16 MFMA GEMM [16384,1024] x [1024,2048]^T with gate-interleaved
// weight packing (epilogue needs no cross-lane traffic). A (= [x|h]) is
// staged f32 -> LDS via async global_load_lds with an XOR chunk swizzle
// (conflict-free ds_read_b128), converted to bf16 at fragment-read time.

#define BATCH 16384
#define KDIM  1024
#define NPK   2048
#define HIDN  512

#define BM 128
#define BN 128
#define BK 32

typedef __bf16 bf16x8 __attribute__((ext_vector_type(8)));
typedef float  f32x4  __attribute__((ext_vector_type(4)));

__device__ __forceinline__ unsigned short f2bf(float f) {
  unsigned int u = __builtin_bit_cast(unsigned int, f);
  u += 0x7fffu + ((u >> 16) & 1u);   // RNE
  return (unsigned short)(u >> 16);
}

__device__ __forceinline__ float fast_sigmoid(float x) {
  return __builtin_amdgcn_rcpf(1.0f + __expf(-x));
}
__device__ __forceinline__ float fast_tanh(float x) {
  return 1.0f - 2.0f * __builtin_amdgcn_rcpf(1.0f + __expf(2.0f * x));
}

// async global->LDS, 16 B per lane; LDS dest = wave-uniform base + lane*16,
// global address is PER-LANE (gather) -- this implements the swizzle for free.
__device__ __forceinline__ void gload_lds16(const void* gp, void* lds_wave_base) {
  auto g = (const __attribute__((address_space(1))) unsigned int*)(unsigned long long)gp;
  auto l = (__attribute__((address_space(3))) unsigned int*)
           (unsigned int)(unsigned long long)lds_wave_base;
  __builtin_amdgcn_global_load_lds(g, l, 16, 0, 0);
}

// ---------------- weight pack (once per launch, tiny: 12 MB traffic) -------

struct GatePtrs {
  const float* wx[4];  // gate order: i, g, f, o
  const float* wh[4];
  const float* bx[4];
  const float* bh[4];
};

// packed row r = b*128 + wn*64 + gate*16 + jl ; j = b*32 + wn*16 + jl
__global__ __launch_bounds__(256) void pack_w(GatePtrs P,
                                              unsigned short* __restrict__ W,
                                              float* __restrict__ bias) {
  int c = blockIdx.x * 256 + threadIdx.x;   // chunk of 8, 128 chunks per row
  int r = c >> 7;
  int k = (c & 127) << 3;
  int b    = r >> 7;
  int rem  = r & 127;
  int wn   = (rem >> 6) & 1;
  int gate = (rem >> 4) & 3;
  int jl   = rem & 15;
  int j = b * 32 + wn * 16 + jl;
  const float* src = (k < 512) ? (P.wx[gate] + j * 512 + k)
                               : (P.wh[gate] + j * 512 + (k - 512));
  float4 lo = ((const float4*)src)[0];
  float4 hi = ((const float4*)src)[1];
  union { unsigned short s[8]; uint4 u; } o;
  o.s[0]=f2bf(lo.x); o.s[1]=f2bf(lo.y); o.s[2]=f2bf(lo.z); o.s[3]=f2bf(lo.w);
  o.s[4]=f2bf(hi.x); o.s[5]=f2bf(hi.y); o.s[6]=f2bf(hi.z); o.s[7]=f2bf(hi.w);
  ((uint4*)W)[c] = o.u;
  if ((c & 127) == 0) bias[r] = P.bx[gate][j] + P.bh[gate][j];
}

// ---------------- fused GEMM + LSTM epilogue ----------------

__global__ __launch_bounds__(256) void lstm_gemm(
    const float* __restrict__ x,             // [16384,512] f32 (A cols 0..511)
    const float* __restrict__ h,             // [16384,512] f32 (A cols 512..1023)
    const unsigned short* __restrict__ W,    // [2048,1024] bf16 packed N x K
    const float* __restrict__ bias,          // [2048] packed
    const float* __restrict__ Cin,           // [16384,512]
    float* __restrict__ Hout,                // [16384,512]
    float* __restrict__ Cout) {              // [16384,512]
  // A tile: 128 rows x 32 f32 (128 B/row = 8 chunks of 16 B), XOR-swizzled:
  //   LDS chunk pos c holds global chunk q with c = (q + r) & 7.
  // B tile: 128 rows x 32 bf16 (64 B/row = 4 chunks of 16 B), swizzled:
  //   c = q ^ ((r >> 1) & 3).
  __shared__ __align__(16) float          lds_a[BM * BK];   // 16 KB
  __shared__ __align__(16) unsigned short lds_b[BN * BK];   //  8 KB

  const int tid  = threadIdx.x;
  const int lane = tid & 63;
  const int wv   = tid >> 6;     // 0..3
  const int wm   = wv >> 1;      // wave row (2x2)
  const int wn   = wv & 1;       // wave col
  const int bn   = blockIdx.x;   // 0..15  (packed-N tiles)
  const int bm   = blockIdx.y;   // 0..127 (M tiles)

  // ---- staging descriptors ----
  // A: 4 instructions/thread, each wave covers 8 rows x 128 B per instruction.
  int offA[4];                   // f32 index into x/h (kt part added in loop)
  float* ldsA[4];
#pragma unroll
  for (int t = 0; t < 4; ++t) {
    int rloc = wv * 32 + t * 8 + (lane >> 3);          // tile row 0..127
    int q = ((lane & 7) - (lane >> 3)) & 7;            // global 16B chunk
    offA[t] = (bm * 128 + rloc) * 512 + q * 4;
    ldsA[t] = lds_a + (wv * 32 + t * 8) * BK;          // wave-uniform
  }
  // B: 2 instructions/thread, each wave covers 16 rows x 64 B per instruction.
  int offB[2];                   // bf16 index into W
  unsigned short* ldsB[2];
#pragma unroll
  for (int t = 0; t < 2; ++t) {
    int rloc = wv * 32 + t * 16 + (lane >> 2);
    int q = (lane & 3) ^ ((lane >> 3) & 3);
    offB[t] = (bn * 128 + rloc) * KDIM + q * 8;
    ldsB[t] = lds_b + (wv * 32 + t * 16) * BK;         // wave-uniform
  }

  f32x4 acc[4][4] = {};

  const int lrow = lane & 15;            // m/n within fragment
  const int kq   = lane >> 4;            // k-group 0..3 (8 elems each)

  for (int kt = 0; kt < KDIM / BK; ++kt) {
    const float* asrc = (kt < 16) ? x : h;
    const int ak = (kt & 15) * BK;
#pragma unroll
    for (int t = 0; t < 4; ++t) gload_lds16(asrc + offA[t] + ak, ldsA[t]);
#pragma unroll
    for (int t = 0; t < 2; ++t) gload_lds16(W + offB[t] + kt * BK, ldsB[t]);
    __syncthreads();

    bf16x8 af[4], bf[4];
#pragma unroll
    for (int mi = 0; mi < 4; ++mi) {
      int ra = wm * 64 + mi * 16 + lrow;
      int c1 = (2 * kq + ra) & 7;
      int c2 = (2 * kq + 1 + ra) & 7;
      f32x4 a0 = *reinterpret_cast<const f32x4*>(&lds_a[ra * BK + c1 * 4]);
      f32x4 a1 = *reinterpret_cast<const f32x4*>(&lds_a[ra * BK + c2 * 4]);
      bf16x8 v;
#pragma unroll
      for (int e = 0; e < 4; ++e) { v[e] = (__bf16)a0[e]; v[e + 4] = (__bf16)a1[e]; }
      af[mi] = v;
    }
#pragma unroll
    for (int ni = 0; ni < 4; ++ni) {
      int rn = wn * 64 + ni * 16 + lrow;
      int cb = kq ^ ((lrow >> 1) & 3);
      bf[ni] = *reinterpret_cast<const bf16x8*>(&lds_b[rn * BK + cb * 8]);
    }
#pragma unroll
    for (int mi = 0; mi < 4; ++mi)
#pragma unroll
      for (int ni = 0; ni < 4; ++ni)
        acc[mi][ni] = __builtin_amdgcn_mfma_f32_16x16x32_bf16(
            af[mi], bf[ni], acc[mi][ni], 0, 0, 0);
    __syncthreads();
  }

  // epilogue: ni == gate (0=i,1=g,2=f,3=o); lane's j is fixed; zero x-lane ops.
  const int jl = lane & 15;
  const int j  = bn * 32 + wn * 16 + jl;                 // hidden index
  const int rbase = bm * 128 + wm * 64 + ((lane >> 4) << 2);
  float bv[4];
#pragma unroll
  for (int ni = 0; ni < 4; ++ni)
    bv[ni] = bias[bn * 128 + wn * 64 + ni * 16 + jl];

#pragma unroll
  for (int mi = 0; mi < 4; ++mi) {
#pragma unroll
    for (int r = 0; r < 4; ++r) {
      int row = rbase + mi * 16 + r;
      float iv = fast_sigmoid(acc[mi][0][r] + bv[0]);
      float gv = fast_tanh   (acc[mi][1][r] + bv[1]);
      float fv = fast_sigmoid(acc[mi][2][r] + bv[2]);
      float ov = fast_sigmoid(acc[mi][3][r] + bv[3]);
      float cold = Cin[(size_t)row * HIDN + j];
      float cnew = fv * cold + iv * gv;
      Hout[(size_t)row * HIDN + j] = ov * fast_tanh(cnew);
      Cout[(size_t)row * HIDN + j] = cnew;
    }
  }
}

// ---------------- launch ----------------

extern "C" void kernel_launch(void* const* d_in, const int* in_sizes, int n_in,
                              void* d_out, int out_size, void* d_ws, size_t ws_size,
                              hipStream_t stream) {
  const float* x   = (const float*)d_in[0];
  const float* h   = (const float*)d_in[1];
  const float* c   = (const float*)d_in[2];
  const float* Wxi = (const float*)d_in[3];  const float* bxi = (const float*)d_in[4];
  const float* Wxo = (const float*)d_in[5];  const float* bxo = (const float*)d_in[6];
  const float* Wxf = (const float*)d_in[7];  const float* bxf = (const float*)d_in[8];
  const float* Wxg = (const float*)d_in[9];  const float* bxg = (const float*)d_in[10];
  const float* Whi = (const float*)d_in[11]; const float* bhi = (const float*)d_in[12];
  const float* Who = (const float*)d_in[13]; const float* bho = (const float*)d_in[14];
  const float* Whf = (const float*)d_in[15]; const float* bhf = (const float*)d_in[16];
  const float* Whg = (const float*)d_in[17]; const float* bhg = (const float*)d_in[18];

  char* ws = (char*)d_ws;
  unsigned short* Wpack = (unsigned short*)ws;                        // 4 MB
  float* biasp = (float*)(ws + (size_t)NPK * KDIM * 2);               // 8 KB

  GatePtrs P;
  P.wx[0] = Wxi; P.wx[1] = Wxg; P.wx[2] = Wxf; P.wx[3] = Wxo;
  P.wh[0] = Whi; P.wh[1] = Whg; P.wh[2] = Whf; P.wh[3] = Who;
  P.bx[0] = bxi; P.bx[1] = bxg; P.bx[2] = bxf; P.bx[3] = bxo;
  P.bh[0] = bhi; P.bh[1] = bhg; P.bh[2] = bhf; P.bh[3] = bho;
  pack_w<<<(NPK * KDIM / 8) / 256, 256, 0, stream>>>(P, Wpack, biasp);

  float* Hout = (float*)d_out;
  float* Cout = Hout + (size_t)BATCH * HIDN;
  dim3 grid(NPK / BN, BATCH / BM);
  lstm_gemm<<<grid, 256, 0, stream>>>(x, h, Wpack, biasp, c, Hout, Cout);
}

// Round 3
// 266.646 us; speedup vs baseline: 1.1772x; 1.1772x over previous
//
#include <hip/hip_runtime.h>
#include <cstdint>
#include <cstddef>

// LSTM cell: B=16384, IN=HID=512.
// R3: R1 structure (bf16-packed A, gate-interleaved W, fused epilogue) +
// double-buffered LDS K-loop with ONE barrier per kt so global_load_lds DMA
// for tile kt+1 overlaps ds_read+MFMA of tile kt.

#define BATCH 16384
#define KDIM  1024
#define NPK   2048
#define HIDN  512

#define BM 128
#define BN 128
#define BK 32

typedef __bf16 bf16x8 __attribute__((ext_vector_type(8)));
typedef float  f32x4  __attribute__((ext_vector_type(4)));

__device__ __forceinline__ unsigned short f2bf(float f) {
  unsigned int u = __builtin_bit_cast(unsigned int, f);
  u += 0x7fffu + ((u >> 16) & 1u);   // RNE
  return (unsigned short)(u >> 16);
}

__device__ __forceinline__ float fast_sigmoid(float x) {
  return __builtin_amdgcn_rcpf(1.0f + __expf(-x));
}
__device__ __forceinline__ float fast_tanh(float x) {
  return 1.0f - 2.0f * __builtin_amdgcn_rcpf(1.0f + __expf(2.0f * x));
}

// async global->LDS, 16 B per lane; LDS dest = wave-uniform base + lane*16
__device__ __forceinline__ void gload_lds16(const void* gp, void* lds_wave_base) {
  auto g = (const __attribute__((address_space(1))) unsigned int*)(unsigned long long)gp;
  auto l = (__attribute__((address_space(3))) unsigned int*)
           (unsigned int)(unsigned long long)lds_wave_base;
  __builtin_amdgcn_global_load_lds(g, l, 16, 0, 0);
}

// ---------------- prep kernels ----------------

__global__ __launch_bounds__(256) void pack_a(const float* __restrict__ x,
                                              const float* __restrict__ h,
                                              unsigned short* __restrict__ A) {
  int c = blockIdx.x * 256 + threadIdx.x;   // chunk of 8 elements
  int idx = c << 3;
  int b = idx >> 10;          // row
  int k = idx & 1023;         // col in [0,1024)
  const float* src = (k < 512) ? (x + b * 512 + k) : (h + b * 512 + (k - 512));
  float4 lo = ((const float4*)src)[0];
  float4 hi = ((const float4*)src)[1];
  union { unsigned short s[8]; uint4 u; } o;
  o.s[0]=f2bf(lo.x); o.s[1]=f2bf(lo.y); o.s[2]=f2bf(lo.z); o.s[3]=f2bf(lo.w);
  o.s[4]=f2bf(hi.x); o.s[5]=f2bf(hi.y); o.s[6]=f2bf(hi.z); o.s[7]=f2bf(hi.w);
  ((uint4*)A)[c] = o.u;
}

struct GatePtrs {
  const float* wx[4];  // gate order: i, g, f, o
  const float* wh[4];
  const float* bx[4];
  const float* bh[4];
};

// packed row r = b*128 + wn*64 + gate*16 + jl ; j = b*32 + wn*16 + jl
__global__ __launch_bounds__(256) void pack_w(GatePtrs P,
                                              unsigned short* __restrict__ W,
                                              float* __restrict__ bias) {
  int c = blockIdx.x * 256 + threadIdx.x;   // chunk of 8, 128 chunks per row
  int r = c >> 7;
  int k = (c & 127) << 3;
  int b    = r >> 7;
  int rem  = r & 127;
  int wn   = (rem >> 6) & 1;
  int gate = (rem >> 4) & 3;
  int jl   = rem & 15;
  int j = b * 32 + wn * 16 + jl;
  const float* src = (k < 512) ? (P.wx[gate] + j * 512 + k)
                               : (P.wh[gate] + j * 512 + (k - 512));
  float4 lo = ((const float4*)src)[0];
  float4 hi = ((const float4*)src)[1];
  union { unsigned short s[8]; uint4 u; } o;
  o.s[0]=f2bf(lo.x); o.s[1]=f2bf(lo.y); o.s[2]=f2bf(lo.z); o.s[3]=f2bf(lo.w);
  o.s[4]=f2bf(hi.x); o.s[5]=f2bf(hi.y); o.s[6]=f2bf(hi.z); o.s[7]=f2bf(hi.w);
  ((uint4*)W)[c] = o.u;
  if ((c & 127) == 0) bias[r] = P.bx[gate][j] + P.bh[gate][j];
}

// ---------------- fused GEMM + LSTM epilogue ----------------

__global__ __launch_bounds__(256) void lstm_gemm(
    const unsigned short* __restrict__ A,    // [16384,1024] bf16
    const unsigned short* __restrict__ W,    // [2048,1024] bf16 packed N x K
    const float* __restrict__ bias,          // [2048] packed
    const float* __restrict__ Cin,           // [16384,512]
    float* __restrict__ Hout,                // [16384,512]
    float* __restrict__ Cout) {              // [16384,512]
  __shared__ __align__(16) unsigned short lds_a[2][BM * BK];  // 2 x 8 KB
  __shared__ __align__(16) unsigned short lds_b[2][BN * BK];  // 2 x 8 KB

  const int tid  = threadIdx.x;
  const int lane = tid & 63;
  const int wv   = tid >> 6;     // 0..3
  const int wm   = wv >> 1;      // wave row (2x2)
  const int wn   = wv & 1;       // wave col
  const int bn   = blockIdx.x;   // 0..15  (packed-N tiles)
  const int bm   = blockIdx.y;   // 0..127 (M tiles)

  // staging: each wave covers two 16-row chunks per matrix per K-step
  const int srow = lane >> 2;           // 0..15
  const int scol = (lane & 3) << 3;     // 0,8,16,24 (elements)
  const unsigned short* ga0 = A + (size_t)(bm * 128 + wv * 16 + srow) * KDIM + scol;
  const unsigned short* ga1 = A + (size_t)(bm * 128 + (wv + 4) * 16 + srow) * KDIM + scol;
  const unsigned short* gb0 = W + (size_t)(bn * 128 + wv * 16 + srow) * KDIM + scol;
  const unsigned short* gb1 = W + (size_t)(bn * 128 + (wv + 4) * 16 + srow) * KDIM + scol;
  const int la0 = (wv * 16) * BK;
  const int la1 = ((wv + 4) * 16) * BK;

  f32x4 acc[4][4] = {};

  const int lrow = lane & 15;            // m/n within fragment
  const int kg   = (lane >> 4) << 3;     // k offset within fragment

  // prologue: stage tile 0 into buffer 0
  gload_lds16(ga0, &lds_a[0][la0]);
  gload_lds16(ga1, &lds_a[0][la1]);
  gload_lds16(gb0, &lds_b[0][la0]);
  gload_lds16(gb1, &lds_b[0][la1]);
  ga0 += BK; ga1 += BK; gb0 += BK; gb1 += BK;

  for (int kt = 0; kt < KDIM / BK; ++kt) {
    const int cur = kt & 1;
    // Barrier: compiler drains vmcnt(0) first, so buffer `cur` DMA is done
    // and all waves have finished reading buffer `cur^1` (last iteration).
    __syncthreads();
    if (kt < KDIM / BK - 1) {
      // prefetch tile kt+1 into the other buffer; flies during compute below
      gload_lds16(ga0, &lds_a[cur ^ 1][la0]);
      gload_lds16(ga1, &lds_a[cur ^ 1][la1]);
      gload_lds16(gb0, &lds_b[cur ^ 1][la0]);
      gload_lds16(gb1, &lds_b[cur ^ 1][la1]);
      ga0 += BK; ga1 += BK; gb0 += BK; gb1 += BK;
    }

    bf16x8 af[4], bf[4];
#pragma unroll
    for (int mi = 0; mi < 4; ++mi)
      af[mi] = *reinterpret_cast<const bf16x8*>(
          &lds_a[cur][(wm * 64 + mi * 16 + lrow) * BK + kg]);
#pragma unroll
    for (int ni = 0; ni < 4; ++ni)
      bf[ni] = *reinterpret_cast<const bf16x8*>(
          &lds_b[cur][(wn * 64 + ni * 16 + lrow) * BK + kg]);
#pragma unroll
    for (int mi = 0; mi < 4; ++mi)
#pragma unroll
      for (int ni = 0; ni < 4; ++ni)
        acc[mi][ni] = __builtin_amdgcn_mfma_f32_16x16x32_bf16(
            af[mi], bf[ni], acc[mi][ni], 0, 0, 0);
  }

  // epilogue: ni == gate (0=i,1=g,2=f,3=o); lane's j is fixed; no x-lane ops.
  const int jl = lane & 15;
  const int j  = bn * 32 + wn * 16 + jl;                 // hidden index
  const int rbase = bm * 128 + wm * 64 + ((lane >> 4) << 2);
  float bv[4];
#pragma unroll
  for (int ni = 0; ni < 4; ++ni)
    bv[ni] = bias[bn * 128 + wn * 64 + ni * 16 + jl];

#pragma unroll
  for (int mi = 0; mi < 4; ++mi) {
#pragma unroll
    for (int r = 0; r < 4; ++r) {
      int row = rbase + mi * 16 + r;
      float iv = fast_sigmoid(acc[mi][0][r] + bv[0]);
      float gv = fast_tanh   (acc[mi][1][r] + bv[1]);
      float fv = fast_sigmoid(acc[mi][2][r] + bv[2]);
      float ov = fast_sigmoid(acc[mi][3][r] + bv[3]);
      float cold = Cin[(size_t)row * HIDN + j];
      float cnew = fv * cold + iv * gv;
      Hout[(size_t)row * HIDN + j] = ov * fast_tanh(cnew);
      Cout[(size_t)row * HIDN + j] = cnew;
    }
  }
}

// ---------------- launch ----------------

extern "C" void kernel_launch(void* const* d_in, const int* in_sizes, int n_in,
                              void* d_out, int out_size, void* d_ws, size_t ws_size,
                              hipStream_t stream) {
  const float* x   = (const float*)d_in[0];
  const float* h   = (const float*)d_in[1];
  const float* c   = (const float*)d_in[2];
  const float* Wxi = (const float*)d_in[3];  const float* bxi = (const float*)d_in[4];
  const float* Wxo = (const float*)d_in[5];  const float* bxo = (const float*)d_in[6];
  const float* Wxf = (const float*)d_in[7];  const float* bxf = (const float*)d_in[8];
  const float* Wxg = (const float*)d_in[9];  const float* bxg = (const float*)d_in[10];
  const float* Whi = (const float*)d_in[11]; const float* bhi = (const float*)d_in[12];
  const float* Who = (const float*)d_in[13]; const float* bho = (const float*)d_in[14];
  const float* Whf = (const float*)d_in[15]; const float* bhf = (const float*)d_in[16];
  const float* Whg = (const float*)d_in[17]; const float* bhg = (const float*)d_in[18];

  char* ws = (char*)d_ws;
  unsigned short* Apack = (unsigned short*)ws;                              // 32 MB
  unsigned short* Wpack = (unsigned short*)(ws + (size_t)BATCH * KDIM * 2); // 4 MB
  float* biasp = (float*)(ws + (size_t)BATCH * KDIM * 2 + (size_t)NPK * KDIM * 2);

  pack_a<<<(BATCH * KDIM / 8) / 256, 256, 0, stream>>>(x, h, Apack);

  GatePtrs P;
  P.wx[0] = Wxi; P.wx[1] = Wxg; P.wx[2] = Wxf; P.wx[3] = Wxo;
  P.wh[0] = Whi; P.wh[1] = Whg; P.wh[2] = Whf; P.wh[3] = Who;
  P.bx[0] = bxi; P.bx[1] = bxg; P.bx[2] = bxf; P.bx[3] = bxo;
  P.bh[0] = bhi; P.bh[1] = bhg; P.bh[2] = bhf; P.bh[3] = bho;
  pack_w<<<(NPK * KDIM / 8) / 256, 256, 0, stream>>>(P, Wpack, biasp);

  float* Hout = (float*)d_out;
  float* Cout = Hout + (size_t)BATCH * HIDN;
  dim3 grid(NPK / BN, BATCH / BM);
  lstm_gemm<<<grid, 256, 0, stream>>>(Apack, Wpack, biasp, c, Hout, Cout);
}